// Round 1
// baseline (78.358 us; speedup 1.0000x reference)
//
#include <hip/hip_runtime.h>

// Tree evaluation: N=2048 nodes, node j in [1024,2047] = leaf, [1,1023] = internal.
// Node j internal: val = rotate(homog(V[2j], V[2j+1], frac[2048-2j], frac[2047-2j]), theta[j])
// Node j leaf:     val = rotate(j%2==0 ? phase1[b] : phase2[b], theta[j])
// Output per batch b: node 1's 6-vector. prop_w/prop_f in the reference are dead code.

#define N_NODES 2048

// D = R^T M R, R = [[a,bb,d],[bb,a,-d],[-d,d,e]], M symmetric (m0 m1 m2; m1 m3 m4; m2 m4 m5)
__device__ __forceinline__ void rotate6(const float* m, float4 r, float* o) {
    float a = r.x, bb = r.y, d = r.z, e = r.w;
    float T00 = m[0]*a  + m[1]*bb - m[2]*d;
    float T01 = m[0]*bb + m[1]*a  + m[2]*d;
    float T02 = (m[0]-m[1])*d + m[2]*e;
    float T10 = m[1]*a  + m[3]*bb - m[4]*d;
    float T11 = m[1]*bb + m[3]*a  + m[4]*d;
    float T12 = (m[1]-m[3])*d + m[4]*e;
    float T20 = m[2]*a  + m[4]*bb - m[5]*d;
    float T21 = m[2]*bb + m[4]*a  + m[5]*d;
    float T22 = (m[2]-m[4])*d + m[5]*e;
    o[0] = a*T00 + bb*T10 - d*T20;
    o[1] = a*T01 + bb*T11 - d*T21;
    o[2] = a*T02 + bb*T12 - d*T22;
    o[3] = bb*T01 + a*T11 + d*T21;
    o[4] = bb*T02 + a*T12 + d*T22;
    o[5] = (T02 - T12)*d + e*T22;
}

__device__ __forceinline__ void homog6(const float* D1, const float* D2,
                                       float f1, float f2, float* o) {
    float gamma = f1*D2[0] + f2*D1[0];
    float g = (gamma == 0.0f) ? 1.0f : gamma;
    float rg = 1.0f / g;
    float ff = f1*f2*rg;
    o[0] = D1[0]*D2[0]*rg;
    o[1] = (f1*D1[1]*D2[0] + f2*D2[1]*D1[0])*rg;
    o[2] = (f1*D1[2]*D2[0] + f2*D2[2]*D1[0])*rg;
    float t1 = D1[1]-D2[1];
    float t2 = D1[2]-D2[2];
    o[3] = f1*D1[3] + f2*D2[3] - ff*t1*t1;
    o[4] = f1*D1[4] + f2*D2[4] - ff*t2*t1;
    o[5] = f1*D1[5] + f2*D2[5] - ff*t2*t2;
}

// level-9 node j9 from its two leaf children (2*j9 even -> phase1, 2*j9+1 odd -> phase2)
__device__ __forceinline__ void subtree9(const float* p1, const float* p2,
                                         const float4* __restrict__ rot,
                                         const float2* __restrict__ fr,
                                         int j9, float* outD) {
    float L[6], R[6], H[6];
    rotate6(p1, rot[2*j9],   L);
    rotate6(p2, rot[2*j9+1], R);
    float2 f = fr[j9];
    homog6(L, R, f.x, f.y, H);
    rotate6(H, rot[j9], outD);
}

__global__ void setup_kernel(const float* __restrict__ theta,
                             const float* __restrict__ fractions,
                             float4* __restrict__ rot, float2* __restrict__ fr) {
    int j = blockIdx.x * blockDim.x + threadIdx.x;
    if (j >= 1 && j < N_NODES) {
        float t = theta[j];
        float c = cosf(t), s = sinf(t);
        float a = c*c, bb = s*s;
        float d = sqrtf(2.0f) * c * s;
        rot[j] = make_float4(a, bb, d, a - bb);
    }
    if (j >= 1 && j < N_NODES/2) {
        fr[j] = make_float2(fractions[N_NODES - 2*j], fractions[N_NODES - 2*j - 1]);
    }
}

__global__ __launch_bounds__(256) void tree_kernel(
    const float* __restrict__ phase1, const float* __restrict__ phase2,
    const float4* __restrict__ rot, const float2* __restrict__ fr,
    float* __restrict__ out)
{
    // SoA planes: V[k][j] holds component k of node j, j in [1, 512)+[256,512) writes.
    __shared__ float V[6][512];
    const int b = blockIdx.x;
    const int tid = threadIdx.x;

    float p1[6], p2[6];
#pragma unroll
    for (int k = 0; k < 6; ++k) { p1[k] = phase1[b*6+k]; p2[k] = phase2[b*6+k]; }

    // Fused bottom two levels: thread tid computes level-8 node j8 = 256+tid
    // from its 4-leaf subtree entirely in registers.
    {
        int j8 = 256 + tid;
        float DA[6], DB[6], Dh[6], Dn[6];
        subtree9(p1, p2, rot, fr, 2*j8,   DA);
        subtree9(p1, p2, rot, fr, 2*j8+1, DB);
        float2 f = fr[j8];
        homog6(DA, DB, f.x, f.y, Dh);
        rotate6(Dh, rot[j8], Dn);
#pragma unroll
        for (int k = 0; k < 6; ++k) V[k][j8] = Dn[k];
    }
    __syncthreads();

    // Levels 7..1: node j in [w, 2w), children at LDS indices 2j, 2j+1.
#pragma unroll 1
    for (int Lw = 128; Lw >= 2; Lw >>= 1) {
        if (tid < Lw) {
            int j = Lw + tid;
            float D1[6], D2[6], Dh[6], Dn[6];
#pragma unroll
            for (int k = 0; k < 6; ++k) {
                float2 ch = ((const float2*)&V[k][0])[j];  // V[k][2j], V[k][2j+1]
                D1[k] = ch.x; D2[k] = ch.y;
            }
            float2 f = fr[j];
            homog6(D1, D2, f.x, f.y, Dh);
            rotate6(Dh, rot[j], Dn);
#pragma unroll
            for (int k = 0; k < 6; ++k) V[k][j] = Dn[k];
        }
        __syncthreads();
    }

    // Root: node 1, children nodes 2 and 3.
    if (tid == 0) {
        float D1[6], D2[6], Dh[6], Dn[6];
#pragma unroll
        for (int k = 0; k < 6; ++k) {
            float2 ch = ((const float2*)&V[k][0])[1];
            D1[k] = ch.x; D2[k] = ch.y;
        }
        float2 f = fr[1];
        homog6(D1, D2, f.x, f.y, Dh);
        rotate6(Dh, rot[1], Dn);
#pragma unroll
        for (int k = 0; k < 6; ++k) out[b*6 + k] = Dn[k];
    }
}

extern "C" void kernel_launch(void* const* d_in, const int* in_sizes, int n_in,
                              void* d_out, int out_size, void* d_ws, size_t ws_size,
                              hipStream_t stream) {
    const float* phase1    = (const float*)d_in[0];
    const float* phase2    = (const float*)d_in[1];
    const float* theta     = (const float*)d_in[2];
    // d_in[3] activation, d_in[4] weight, d_in[6] left, d_in[7] right: dead code / fixed tree
    const float* fractions = (const float*)d_in[5];
    float* out = (float*)d_out;

    const int B = in_sizes[0] / 6;

    float4* rot = (float4*)d_ws;                                    // 2048 * 16B = 32 KB
    float2* fr  = (float2*)((char*)d_ws + N_NODES * sizeof(float4)); // 1024 * 8B = 8 KB

    hipLaunchKernelGGL(setup_kernel, dim3((N_NODES + 255) / 256), dim3(256), 0, stream,
                       theta, fractions, rot, fr);
    hipLaunchKernelGGL(tree_kernel, dim3(B), dim3(256), 0, stream,
                       phase1, phase2, rot, fr, out);
}